// Round 2
// baseline (979.519 us; speedup 1.0000x reference)
//
#include <hip/hip_runtime.h>
#include <hip/hip_bf16.h>

// Reference: c = associative_scan(combine, (a,b), axis=1) with
//   combine((A,B),(a,b)) = (A*a, a*B + b)
// == first-order linear recurrence c_t = a_t * c_{t-1} + b_t (c_{-1}=0),
// per (batch, unit). inputs: (16, 2048, 4096) f32; a = [:,:,:2048],
// b = [:,:,2048:]; output: (16, 2048, 2048) f32.
//
// Traffic-optimal plan: ONE pass over the input (512 MiB in, 256 MiB out,
// ~128 us floor at 6.3 TB/s). One thread per (batch,unit) sequence, serial
// over t. Consecutive threads = consecutive units -> every load/store is a
// 256 B wave-coalesced access. Chunk-unroll of 32 issues 64 independent
// loads (256 B/lane in flight) before the dependent FMA chain, covering
// ~900-cycle HBM latency at the 2-waves/CU occupancy this implies.

constexpr int T   = 2048;      // scan length (axis=1)
constexpr int U   = 2048;      // UNITS
constexpr int ROW = 2 * U;     // floats per (batch, t) row of the input
constexpr int CH  = 32;        // t-chunk per unrolled body

__global__ __launch_bounds__(64)
void tempo_scan_kernel(const float* __restrict__ in, float* __restrict__ out,
                       int nseq) {
    const int tid = blockIdx.x * 64 + threadIdx.x;
    if (tid >= nseq) return;
    const int batch = tid >> 11;          // tid / U
    const int u     = tid & (U - 1);      // tid % U

    const float* __restrict__ pin  = in  + (size_t)batch * T * ROW + u;
    float*       __restrict__ pout = out + (size_t)batch * T * U   + u;

    float c = 0.0f;

    for (int t0 = 0; t0 < T; t0 += CH) {
        float av[CH], bv[CH];
        // Issue all 2*CH independent loads before the dependent chain.
        #pragma unroll
        for (int i = 0; i < CH; ++i) {
            const float* p = pin + (size_t)(t0 + i) * ROW;
            av[i] = p[0];   // a[batch, t0+i, u]
            bv[i] = p[U];   // b[batch, t0+i, u]
        }
        // Serial recurrence + coalesced stores.
        #pragma unroll
        for (int i = 0; i < CH; ++i) {
            c = fmaf(av[i], c, bv[i]);
            pout[(size_t)(t0 + i) * U] = c;
        }
    }
}

extern "C" void kernel_launch(void* const* d_in, const int* in_sizes, int n_in,
                              void* d_out, int out_size, void* d_ws, size_t ws_size,
                              hipStream_t stream) {
    const float* in  = (const float*)d_in[0];
    float*       out = (float*)d_out;

    // nseq = total elements / (T * 2) = batch * U sequences.
    const int nseq = (int)((long long)in_sizes[0] / (2 * T));
    const int blocks = (nseq + 63) / 64;   // 512 for the reference shape

    tempo_scan_kernel<<<dim3(blocks), dim3(64), 0, stream>>>(in, out, nseq);
}

// Round 3
// 759.068 us; speedup vs baseline: 1.2904x; 1.2904x over previous
//
#include <hip/hip_runtime.h>
#include <hip/hip_bf16.h>

// c_t = a_t * c_{t-1} + b_t along axis=1, per (batch, unit).
// inputs: (16, 2048, 4096) f32, a = [:,:,:2048], b = [:,:,2048:]
// output: (16, 2048, 2048) f32
//
// One thread per (batch,unit) sequence (32768 threads = 2 waves/CU), serial
// over t. Round-2 profile showed latency-bound (1.24 TB/s, VGPR=40): the
// compiler fused the load batch into the FMA chain, leaving ~4 loads in
// flight. This version forces MLP:
//   - sched_barrier(0) pins all chunk loads before the dependent chain
//   - double-buffered chunks (statically indexed -> stays in VGPRs) keep
//     ~64 loads/wave outstanding across the chunk boundary
//   - nontemporal stores keep output write-allocate from evicting the
//     L3-resident half of the input (round-2 FETCH was 256 MiB, not 512)

constexpr int T   = 2048;      // scan length
constexpr int U   = 2048;      // UNITS
constexpr int ROW = 2 * U;     // floats per (batch, t) input row
constexpr int CH  = 16;        // t-steps per buffer (2 buffers in flight)

__global__ __launch_bounds__(64)
void tempo_scan_kernel(const float* __restrict__ in, float* __restrict__ out,
                       int nseq) {
    const int tid = blockIdx.x * 64 + threadIdx.x;
    if (tid >= nseq) return;
    const int batch = tid >> 11;          // tid / U
    const int u     = tid & (U - 1);      // tid % U

    const float* __restrict__ pin  = in  + (size_t)batch * T * ROW + u;
    float*       __restrict__ pout = out + (size_t)batch * T * U   + u;

    float c = 0.0f;
    float a0[CH], b0[CH], a1[CH], b1[CH];

#define LOAD_CHUNK(A, B, T0)                                          \
    _Pragma("unroll")                                                 \
    for (int i = 0; i < CH; ++i) {                                    \
        const float* p = pin + (size_t)((T0) + i) * ROW;              \
        (A)[i] = p[0];                                                \
        (B)[i] = p[U];                                                \
    }

#define COMPUTE_CHUNK(A, B, T0)                                       \
    _Pragma("unroll")                                                 \
    for (int i = 0; i < CH; ++i) {                                    \
        c = fmaf((A)[i], c, (B)[i]);                                  \
        __builtin_nontemporal_store(c, pout + (size_t)((T0) + i) * U);\
    }

    LOAD_CHUNK(a0, b0, 0)
    __builtin_amdgcn_sched_barrier(0);

    #pragma unroll 1
    for (int t0 = 0; t0 < T; t0 += 2 * CH) {
        // prefetch odd chunk while even chunk computes
        LOAD_CHUNK(a1, b1, t0 + CH)
        __builtin_amdgcn_sched_barrier(0);
        COMPUTE_CHUNK(a0, b0, t0)
        // prefetch next even chunk while odd chunk computes
        if (t0 + 2 * CH < T) {
            LOAD_CHUNK(a0, b0, t0 + 2 * CH)
        }
        __builtin_amdgcn_sched_barrier(0);
        COMPUTE_CHUNK(a1, b1, t0 + CH)
    }

#undef LOAD_CHUNK
#undef COMPUTE_CHUNK
}

extern "C" void kernel_launch(void* const* d_in, const int* in_sizes, int n_in,
                              void* d_out, int out_size, void* d_ws, size_t ws_size,
                              hipStream_t stream) {
    const float* in  = (const float*)d_in[0];
    float*       out = (float*)d_out;

    const int nseq   = (int)((long long)in_sizes[0] / (2 * T)); // batch * U
    const int blocks = (nseq + 63) / 64;                        // 512

    tempo_scan_kernel<<<dim3(blocks), dim3(64), 0, stream>>>(in, out, nseq);
}